// Round 1
// baseline (78.552 us; speedup 1.0000x reference)
//
#include <hip/hip_runtime.h>

#define NUM_NODES 10000
#define TSTEPS 1440
#define VCOLS 360   // 1440 / 4 float4 columns
#define ROWS_PER_BLOCK 20
#define NBLOCKS 500  // 500 * 20 = 10000 rows exactly

// Stage 0: zero the per-column accumulators in workspace (ws is poisoned 0xAA
// once before timing and never re-poisoned — must clear every call).
__global__ void zero_ws_kernel(float* __restrict__ ws) {
    int t = blockIdx.x * blockDim.x + threadIdx.x;
    if (t < TSTEPS) ws[t] = 0.0f;
}

// Stage 1: column-sum of noise [NUM_NODES, TSTEPS].
// Each thread owns one float4 column (4 scalar columns); lanes within a wave
// read 64 consecutive float4 per row-step -> 1 KiB contiguous, fully coalesced.
// Each block reduces ROWS_PER_BLOCK rows locally, then one atomicAdd per
// scalar column (500 atomics/address total, spread over 1440 addresses).
__global__ __launch_bounds__(384) void col_sum_kernel(
        const float* __restrict__ noise, float* __restrict__ ws) {
    int vc = threadIdx.x;
    if (vc >= VCOLS) return;
    int r0 = blockIdx.x * ROWS_PER_BLOCK;
    int r1 = r0 + ROWS_PER_BLOCK;
    if (r1 > NUM_NODES) r1 = NUM_NODES;

    const float4* __restrict__ p = (const float4*)noise;
    float4 acc = make_float4(0.f, 0.f, 0.f, 0.f);
    #pragma unroll 4
    for (int i = r0; i < r1; ++i) {
        float4 v = p[(size_t)i * VCOLS + vc];
        acc.x += v.x; acc.y += v.y; acc.z += v.z; acc.w += v.w;
    }
    int c = vc * 4;
    atomicAdd(&ws[c + 0], acc.x);
    atomicAdd(&ws[c + 1], acc.y);
    atomicAdd(&ws[c + 2], acc.z);
    atomicAdd(&ws[c + 3], acc.w);
}

// Stage 2: epilogue.
// overall[t] = 0.8 * colmean_noise[t] + 0.5 + 0.3*sin(2*pi*(10/3600)*time[t])
//   (the mean-over-nodes of sin(theta_t + i*2pi/N) is exactly 0: full circle
//    of equally spaced phases -> sum of N-th roots of unity = 0)
// encrypted[t] = sin(0.5 * overall[t])
// d_out layout: [0,1440) = encrypted, [1440,2880) = overall.
__global__ void finalize_kernel(const float* __restrict__ time_tensor,
                                const float* __restrict__ ws,
                                float* __restrict__ out) {
    int t = blockIdx.x * blockDim.x + threadIdx.x;
    if (t >= TSTEPS) return;
    const float TWO_PI = 6.2831853071795864769f;
    const float BRAINWAVE_FREQ = 10.0f / 3600.0f;
    float tm = time_tensor[t];
    float brain = 0.3f * sinf(TWO_PI * BRAINWAVE_FREQ * tm);
    float overall = 0.8f * (ws[t] * (1.0f / NUM_NODES)) + 0.5f + brain;
    out[TSTEPS + t] = overall;
    out[t] = sinf(0.5f * overall);
}

extern "C" void kernel_launch(void* const* d_in, const int* in_sizes, int n_in,
                              void* d_out, int out_size, void* d_ws, size_t ws_size,
                              hipStream_t stream) {
    const float* time_tensor = (const float*)d_in[0];   // [1440]
    const float* noise       = (const float*)d_in[1];   // [10000, 1440]
    float* out = (float*)d_out;                         // [2880]
    float* ws  = (float*)d_ws;                          // >= 1440 floats

    zero_ws_kernel<<<(TSTEPS + 255) / 256, 256, 0, stream>>>(ws);
    col_sum_kernel<<<NBLOCKS, 384, 0, stream>>>(noise, ws);
    finalize_kernel<<<(TSTEPS + 255) / 256, 256, 0, stream>>>(time_tensor, ws, out);
}